// Round 6
// baseline (956.681 us; speedup 1.0000x reference)
//
#include <hip/hip_runtime.h>
#include <math.h>

// EntNet forward on MI355X.
// Sizes: VOC=32000, MEM=128, NSLOTS=20, NSENT=128, MAXLEN=32, QLEN=16, ANSLEN=8, B=64
//
// R5 post-mortem: scan was LDS-instruction-issue bound (~8100 cyc/step/CU):
// B-fragment re-reads (32 b128/wave/step of STATIC weights) + 64 scattered
// update ops. R6: (1) 32x32x16 MFMA -> one C tile/wave, weight fragments live
// in 64 VGPRs (zero per-step B traffic; 16x16 tiling would need 128 regs --
// over the clamp R2/R3 proved). (2) state packed (hi16|lo16) in one u32 ->
// update = 16 b32 reads + 16 b32 writes; v_perm unpack feeds MFMA A-frags.
// (3) gate's s.key dot hoisted to prep (SK table). 2 barriers/step unchanged.

typedef __attribute__((ext_vector_type(8)))  short bf16x8;
typedef __attribute__((ext_vector_type(16))) float f32x16;

__device__ __forceinline__ unsigned short f2bh(float x) {   // f32 -> bf16 RNE
    unsigned int u = __float_as_uint(x);
    u += 0x7FFFu + ((u >> 16) & 1u);
    return (unsigned short)(u >> 16);
}
__device__ __forceinline__ float bh2f(unsigned short h) {
    return __uint_as_float(((unsigned int)h) << 16);
}
// packed word w = (hi16<<16)|lo16 ; value = bh2f(hi) + bh2f(lo)
__device__ __forceinline__ float unpack_w(unsigned int w) {
    return __uint_as_float(w & 0xFFFF0000u) + __uint_as_float(w << 16);
}
__device__ __forceinline__ unsigned int pack_w(float x) {
    const unsigned short h = f2bh(x);
    const unsigned short l = f2bh(x - bh2f(h));
    return ((unsigned int)h << 16) | (unsigned int)l;
}

// ---------------------------------------------------------------- prep
__global__ __launch_bounds__(128) void prep_kernel(
    const int* __restrict__ ids, const int* __restrict__ ques, const int* __restrict__ ans,
    const float* __restrict__ E, const float* __restrict__ Ww, const float* __restrict__ Wb,
    const float* __restrict__ Vw, const float* __restrict__ Vb, const float* __restrict__ skeys,
    float* __restrict__ sT, float* __restrict__ WsT, float* __restrict__ vkey,
    float* __restrict__ qv, float* __restrict__ a1v, float* __restrict__ a2v,
    float* __restrict__ SK)
{
    const int bi  = blockIdx.x;
    const int tid = threadIdx.x;   // 128
    __shared__ float s_l[8][132];
    __shared__ float sk_l[20 * 132];
    __shared__ float k_l[128];
    if (bi < 1024) {
        const int b = bi >> 4;
        const int g = bi & 15;
        for (int r = tid; r < 2560; r += 128) sk_l[(r >> 7) * 132 + (r & 127)] = skeys[r];
        for (int tt = 0; tt < 8; ++tt) {
            const int t     = g * 8 + tt;
            const int token = ids[b * 4096 + t];
            const float v   = E[token * 128 + tid];
            s_l[tt][tid] = v;
            sT[(t * 64 + b) * 128 + tid] = v;         // layout (t, b, m)
        }
        __syncthreads();
        // Ws rows
        float acc[8];
        const float wbn = Wb[tid];
        #pragma unroll
        for (int i = 0; i < 8; ++i) acc[i] = wbn;
        const float4* wrow = (const float4*)(Ww + tid * 128);
        for (int m4 = 0; m4 < 32; ++m4) {
            const float4 w = wrow[m4];
            #pragma unroll
            for (int tt = 0; tt < 8; ++tt) {
                acc[tt] += s_l[tt][m4*4+0]*w.x + s_l[tt][m4*4+1]*w.y
                         + s_l[tt][m4*4+2]*w.z + s_l[tt][m4*4+3]*w.w;
            }
        }
        for (int tt = 0; tt < 8; ++tt)
            WsT[((g*8+tt) * 64 + b) * 128 + tid] = acc[tt];     // layout (t, b, n)
        // SK[j][t][b] = dot(s_t[b], skeys[j])  (gate key-dot, hoisted from scan)
        for (int idx = tid; idx < 160; idx += 128) {
            const int tt = idx / 20;
            const int jj = idx - tt * 20;
            float d = 0.f;
            for (int m = 0; m < 128; ++m) d += s_l[tt][m] * sk_l[jj * 132 + m];
            SK[(jj * 128 + (g*8 + tt)) * 64 + b] = d;
        }
    } else if (bi < 1044) {
        const int j = bi - 1024;
        k_l[tid] = skeys[j * 128 + tid];
        __syncthreads();
        float acc = Vb[tid];
        const float4* vrow = (const float4*)(Vw + tid * 128);
        for (int m4 = 0; m4 < 32; ++m4) {
            const float4 w = vrow[m4];
            acc += k_l[m4*4]*w.x + k_l[m4*4+1]*w.y + k_l[m4*4+2]*w.z + k_l[m4*4+3]*w.w;
        }
        vkey[j * 128 + tid] = acc;
    } else {
        const int b = bi - 1044;
        float sq = 0.f, s1 = 0.f, s2 = 0.f;
        for (int i = 0; i < 16; ++i) sq += E[ques[b*16+i] * 128 + tid];
        for (int i = 0; i < 8;  ++i) s1 += E[ans[(b*8+i)*2+0] * 128 + tid];
        for (int i = 0; i < 8;  ++i) s2 += E[ans[(b*8+i)*2+1] * 128 + tid];
        qv [b*128+tid] = sq * (1.f/16.f);
        a1v[b*128+tid] = s1 * 0.125f;
        a2v[b*128+tid] = s2 * 0.125f;
    }
}

// ---------------------------------------------------------------- scan (MFMA 32x32)
// One block per slot j. 512 threads = 8 waves; wave = (bt2 = wave&1, nt2 = wave>>1).
// Each wave owns ONE 32x32 C tile: C[b][n], b in bt2*32..+31, n in nt2*32..+31.
//   B operand (weights, hi/lo bf16) lives in 64 VGPRs, loaded once from global.
//   A operand (state) read from packed LDS AP: word = (hi16<<16)|lo16 of U[b][m];
//     AP stride 132 words (!= 0 mod 32/4 -> conflict-free b128 column reads).
//   3 MFMAs per kc: AhBh + AhBl + AlBh (rel err ~2^-16); fp32 accum.
// C/D layout [verified m74/m101]: col = lane&31, row = (reg&3)+8*(reg>>2)+4*(lane>>5).
// A layout: row = lane&31, k = (lane>>5)*8 + j  (16x16-verified pattern extended).
// State lives ONLY as the packed pair (recon err 2^-18/step). 2 barriers/step.
__global__ __launch_bounds__(512, 1) void scan_kernel(
    const float* __restrict__ sT, const float* __restrict__ WsT,
    const float* __restrict__ vkey, const float* __restrict__ Uw,
    const float* __restrict__ Ub, const float* __restrict__ SK,
    float* __restrict__ h_out)
{
    __shared__ unsigned int AP[64 * 132];   // packed state, stride 132
    __shared__ float g_l[64];
    __shared__ float wred[8];

    const int j    = blockIdx.x;
    const int tid  = threadIdx.x;        // 512
    const int wave = tid >> 6;           // 0..7
    const int lane = tid & 63;
    const int l32  = lane & 31;
    const int q    = lane >> 5;          // 0..1
    const int bt2  = wave & 1;           // b half
    const int nt2  = wave >> 1;          // n quarter
    const int n    = nt2 * 32 + l32;     // owned output column
    const int gb   = tid >> 3;           // gate: batch row 0..63
    const int gm   = (tid & 7) * 16;     // gate: m-slice (16 words)

    // ---- one-time: weight fragments -> 64 VGPRs ----
    bf16x8 b_h[8], b_l[8];
    {
        const int k0 = q * 8;
        #pragma unroll
        for (int kc = 0; kc < 8; ++kc) {
            const float* src = Uw + n * 128 + kc * 16 + k0;
            #pragma unroll
            for (int e = 0; e < 8; ++e) {
                const float x = src[e];
                const unsigned short h = f2bh(x);
                b_h[kc][e] = (short)h;
                b_l[kc][e] = (short)f2bh(x - bh2f(h));
            }
        }
    }
    for (int i = tid; i < 64 * 132; i += 512) AP[i] = 0u;
    const float ubv = Ub[n] + vkey[j * 128 + n];
    __syncthreads();

    float inv_s = 1.f;                   // true mem = inv_s * recon(AP)

    for (int t = 0; t < 128; ++t) {
        // ---- gate: g[b] = sigmoid(inv*dot(s_t[b],U[b]) + SK[j][t][b]) ----
        {
            const uint4* u4 = (const uint4*)(AP + gb * 132 + gm);
            const float4* s4 = (const float4*)(sT + (t*64 + gb)*128 + gm);
            float d1 = 0.f;
            #pragma unroll
            for (int c = 0; c < 4; ++c) {
                const uint4  uw = u4[c];
                const float4 sv = s4[c];
                d1 += sv.x * unpack_w(uw.x) + sv.y * unpack_w(uw.y)
                    + sv.z * unpack_w(uw.z) + sv.w * unpack_w(uw.w);
            }
            d1 += __shfl_xor(d1, 1, 64);
            d1 += __shfl_xor(d1, 2, 64);
            d1 += __shfl_xor(d1, 4, 64);
            const float sk = SK[(j*128 + t)*64 + gb];
            const float g  = 1.f / (1.f + expf(-(inv_s * d1 + sk)));
            if ((tid & 7) == 0) g_l[gb] = g;
        }

        // ---- MFMA: acc = U(32b x 128m) . W(32n x 128m)^T tile ----
        f32x16 acc = {0.f,0.f,0.f,0.f,0.f,0.f,0.f,0.f,
                      0.f,0.f,0.f,0.f,0.f,0.f,0.f,0.f};
        {
            const int arow = (bt2*32 + l32) * 132;
            const int k0   = q * 8;
            #pragma unroll
            for (int kc = 0; kc < 8; ++kc) {
                const uint4 p0 = *(const uint4*)(AP + arow + kc*16 + k0);
                const uint4 p1 = *(const uint4*)(AP + arow + kc*16 + k0 + 4);
                bf16x8 ah, al;
                // dword d of ah = [hi(w_{2d+1}) : hi(w_{2d})]; al likewise with lo
                unsigned int* ahd = (unsigned int*)&ah;
                unsigned int* ald = (unsigned int*)&al;
                ahd[0] = __builtin_amdgcn_perm(p0.y, p0.x, 0x07060302u);
                ald[0] = __builtin_amdgcn_perm(p0.y, p0.x, 0x05040100u);
                ahd[1] = __builtin_amdgcn_perm(p0.w, p0.z, 0x07060302u);
                ald[1] = __builtin_amdgcn_perm(p0.w, p0.z, 0x05040100u);
                ahd[2] = __builtin_amdgcn_perm(p1.y, p1.x, 0x07060302u);
                ald[2] = __builtin_amdgcn_perm(p1.y, p1.x, 0x05040100u);
                ahd[3] = __builtin_amdgcn_perm(p1.w, p1.z, 0x07060302u);
                ald[3] = __builtin_amdgcn_perm(p1.w, p1.z, 0x05040100u);
                acc = __builtin_amdgcn_mfma_f32_32x32x16_bf16(ah, b_h[kc], acc, 0, 0, 0);
                acc = __builtin_amdgcn_mfma_f32_32x32x16_bf16(ah, b_l[kc], acc, 0, 0, 0);
                acc = __builtin_amdgcn_mfma_f32_32x32x16_bf16(al, b_h[kc], acc, 0, 0, 0);
            }
        }
        __syncthreads();   // B1: all reads of old AP complete; g_l visible

        // ---- update owned (b, n) entries in C layout ----
        const float4 gA = *(const float4*)(g_l + bt2*32 + 4*q + 0);
        const float4 gB = *(const float4*)(g_l + bt2*32 + 4*q + 8);
        const float4 gC = *(const float4*)(g_l + bt2*32 + 4*q + 16);
        const float4 gD = *(const float4*)(g_l + bt2*32 + 4*q + 24);
        const float gr[16] = {gA.x,gA.y,gA.z,gA.w, gB.x,gB.y,gB.z,gB.w,
                              gC.x,gC.y,gC.z,gC.w, gD.x,gD.y,gD.z,gD.w};
        float ssq = 0.f;
        #pragma unroll
        for (int r = 0; r < 16; ++r) {
            const int brow = bt2*32 + 4*q + (r & 3) + 8*(r >> 2);
            const float ws = WsT[(t*64 + brow)*128 + n];
            const unsigned int wold = AP[brow*132 + n];
            float hr = fmaf(inv_s, acc[r], ubv + ws);
            hr = fmaxf(hr, 0.f);                          // h_cand
            const float x = fmaf(inv_s, unpack_w(wold), gr[r] * hr);
            AP[brow*132 + n] = pack_w(x);
            ssq = fmaf(x, x, ssq);
        }
        #pragma unroll
        for (int m = 1; m < 64; m <<= 1) ssq += __shfl_xor(ssq, m, 64);
        if (lane == 0) wred[wave] = ssq;
        __syncthreads();   // B2: AP writes + wave partials visible
        const float4 w0 = *(const float4*)(wred);
        const float4 w1 = *(const float4*)(wred + 4);
        inv_s = 1.f / sqrtf(w0.x+w0.y+w0.z+w0.w + w1.x+w1.y+w1.z+w1.w);
        // wred re-written only after next step's B1 -> safe
    }

    // ---- h = inv * recon(AP), layout (b, j, m) ----
    #pragma unroll
    for (int r = 0; r < 16; ++r) {
        const int brow = bt2*32 + 4*q + (r & 3) + 8*(r >> 2);
        h_out[(brow*20 + j)*128 + n] = inv_s * unpack_w(AP[brow*132 + n]);
    }
}

// ---------------------------------------------------------------- final
__global__ __launch_bounds__(128) void final_kernel(
    const float* __restrict__ h, const float* __restrict__ qv,
    const float* __restrict__ a1v, const float* __restrict__ a2v,
    const float* __restrict__ Hw, const float* __restrict__ Hb,
    float* __restrict__ out)
{
    const int b   = blockIdx.x;
    const int tid = threadIdx.x;    // 128
    __shared__ float hb[20][128];
    __shared__ float ql[128];
    __shared__ float ul[128];
    __shared__ float pl[20];
    __shared__ float lgt[20];
    __shared__ float red1[2], red2[2];

    for (int jj = 0; jj < 20; ++jj) hb[jj][tid] = h[(b*20+jj)*128 + tid];
    ql[tid] = qv[b*128 + tid];
    __syncthreads();
    if (tid < 20) {
        float d = 0.f;
        for (int m = 0; m < 128; ++m) d += hb[tid][m] * ql[m];
        lgt[tid] = d;
    }
    __syncthreads();
    if (tid == 0) {
        float mx = lgt[0];
        for (int jj = 1; jj < 20; ++jj) mx = fmaxf(mx, lgt[jj]);
        float s = 0.f;
        for (int jj = 0; jj < 20; ++jj) { const float e = expf(lgt[jj]-mx); pl[jj] = e; s += e; }
        const float is = 1.f / s;
        for (int jj = 0; jj < 20; ++jj) pl[jj] *= is;
    }
    __syncthreads();
    float u = 0.f;
    for (int jj = 0; jj < 20; ++jj) u += pl[jj] * hb[jj][tid];
    ul[tid] = u;
    __syncthreads();
    float acc = ql[tid] + Hb[tid];
    const float4* hwr = (const float4*)(Hw + tid*128);
    for (int m4 = 0; m4 < 32; ++m4) {
        const float4 w = hwr[m4];
        acc += ul[m4*4]*w.x + ul[m4*4+1]*w.y + ul[m4*4+2]*w.z + ul[m4*4+3]*w.w;
    }
    const float r  = fmaxf(acc, 0.f);
    float y1 = r * a1v[b*128+tid];
    float y2 = r * a2v[b*128+tid];
    #pragma unroll
    for (int mask = 1; mask < 64; mask <<= 1) {
        y1 += __shfl_xor(y1, mask, 64);
        y2 += __shfl_xor(y2, mask, 64);
    }
    if ((tid & 63) == 0) { red1[tid>>6] = y1; red2[tid>>6] = y2; }
    __syncthreads();
    if (tid == 0) {
        const float z1 = red1[0] + red1[1];
        const float z2 = red2[0] + red2[1];
        const float mx = fmaxf(z1, z2);
        const float e1 = expf(z1-mx), e2 = expf(z2-mx);
        const float s  = e1 + e2;
        out[b*2+0] = e1 / s;
        out[b*2+1] = e2 / s;
    }
}

// ---------------------------------------------------------------- launch
extern "C" void kernel_launch(void* const* d_in, const int* in_sizes, int n_in,
                              void* d_out, int out_size, void* d_ws, size_t ws_size,
                              hipStream_t stream)
{
    const int*   ids  = (const int*)  d_in[0];
    const int*   ques = (const int*)  d_in[1];
    const int*   ans  = (const int*)  d_in[2];
    const float* E    = (const float*)d_in[3];
    const float* Uw   = (const float*)d_in[4];
    const float* Ubv  = (const float*)d_in[5];
    const float* Vw   = (const float*)d_in[6];
    const float* Vb   = (const float*)d_in[7];
    const float* Ww   = (const float*)d_in[8];
    const float* Wb   = (const float*)d_in[9];
    const float* sk   = (const float*)d_in[10];
    const float* Hw   = (const float*)d_in[11];
    const float* Hb   = (const float*)d_in[12];

    // workspace (floats): sT 1M | WsT 1M | vkey 2560 | qv/a1v/a2v 3*8192 | h 163840 | SK 163840
    float* ws   = (float*)d_ws;
    float* sT   = ws;
    float* WsT  = sT  + 1048576;
    float* vkey = WsT + 1048576;
    float* qv   = vkey + 2560;
    float* a1v  = qv  + 8192;
    float* a2v  = a1v + 8192;
    float* h    = a2v + 8192;
    float* SK   = h   + 163840;

    prep_kernel<<<1108, 128, 0, stream>>>(ids, ques, ans, E, Ww, Wb, Vw, Vb, sk,
                                          sT, WsT, vkey, qv, a1v, a2v, SK);
    scan_kernel<<<20, 512, 0, stream>>>(sT, WsT, vkey, Uw, Ubv, SK, h);
    final_kernel<<<64, 128, 0, stream>>>(h, qv, a1v, a2v, Hw, Hb, (float*)d_out);
}

// Round 7
// 423.742 us; speedup vs baseline: 2.2577x; 2.2577x over previous
//
#include <hip/hip_runtime.h>
#include <math.h>

// EntNet forward on MI355X.
// Sizes: VOC=32000, MEM=128, NSLOTS=20, NSENT=128, MAXLEN=32, QLEN=16, ANSLEN=8, B=64
//
// R6 post-mortem: regression (421->857us scan) was EXPOSED LATENCY: WsT global
// loads moved onto the post-B1 critical path + one 24-long dependent MFMA chain.
// All pipes got quieter (VALUBusy 2.9->2.0, MfmaUtil 1.5->0.7) = latency, not
// throughput. Also established empirically: __launch_bounds__ 2nd arg acts as
// min-BLOCKS/CU -> (512,1) gives a 256-VGPR budget (R2's (512,2) gave 128).
//
// R7: keep R6 structure (weights in 64 VGPRs, packed hi|lo state, 32x32 MFMA);
//  (1) software-pipeline ALL global reads (sv/skv/wsv for t+1 issued in t's
//      update phase; drained at B2; gate+MFMA phase has zero global loads),
//  (2) xprev[16] in registers -> no LDS re-read of old state post-B1,
//  (3) truncated-hi packing (lo absorbs residual; same 2^-16 recon error).

typedef __attribute__((ext_vector_type(8)))  short bf16x8;
typedef __attribute__((ext_vector_type(16))) float f32x16;

__device__ __forceinline__ unsigned short f2bh(float x) {   // f32 -> bf16 RNE
    unsigned int u = __float_as_uint(x);
    u += 0x7FFFu + ((u >> 16) & 1u);
    return (unsigned short)(u >> 16);
}
__device__ __forceinline__ float bh2f(unsigned short h) {
    return __uint_as_float(((unsigned int)h) << 16);
}
// packed word w = hi16|lo16 ; value = f(hi) + f(lo); hi = TRUNCATED bf16,
// lo = RNE bf16 of the residual (absorbs truncation error; recon ~2^-16 |x|)
__device__ __forceinline__ float unpack_w(unsigned int w) {
    return __uint_as_float(w & 0xFFFF0000u) + __uint_as_float(w << 16);
}
__device__ __forceinline__ unsigned int pack_w(float x) {
    const unsigned int hi = __float_as_uint(x) & 0xFFFF0000u;
    const float res = x - __uint_as_float(hi);
    return hi | (unsigned int)f2bh(res);
}

// ---------------------------------------------------------------- prep
__global__ __launch_bounds__(128) void prep_kernel(
    const int* __restrict__ ids, const int* __restrict__ ques, const int* __restrict__ ans,
    const float* __restrict__ E, const float* __restrict__ Ww, const float* __restrict__ Wb,
    const float* __restrict__ Vw, const float* __restrict__ Vb, const float* __restrict__ skeys,
    float* __restrict__ sT, float* __restrict__ WsT, float* __restrict__ vkey,
    float* __restrict__ qv, float* __restrict__ a1v, float* __restrict__ a2v,
    float* __restrict__ SK)
{
    const int bi  = blockIdx.x;
    const int tid = threadIdx.x;   // 128
    __shared__ float s_l[8][132];
    __shared__ float sk_l[20 * 132];
    __shared__ float k_l[128];
    if (bi < 1024) {
        const int b = bi >> 4;
        const int g = bi & 15;
        for (int r = tid; r < 2560; r += 128) sk_l[(r >> 7) * 132 + (r & 127)] = skeys[r];
        for (int tt = 0; tt < 8; ++tt) {
            const int t     = g * 8 + tt;
            const int token = ids[b * 4096 + t];
            const float v   = E[token * 128 + tid];
            s_l[tt][tid] = v;
            sT[(t * 64 + b) * 128 + tid] = v;         // layout (t, b, m)
        }
        __syncthreads();
        // Ws rows
        float acc[8];
        const float wbn = Wb[tid];
        #pragma unroll
        for (int i = 0; i < 8; ++i) acc[i] = wbn;
        const float4* wrow = (const float4*)(Ww + tid * 128);
        for (int m4 = 0; m4 < 32; ++m4) {
            const float4 w = wrow[m4];
            #pragma unroll
            for (int tt = 0; tt < 8; ++tt) {
                acc[tt] += s_l[tt][m4*4+0]*w.x + s_l[tt][m4*4+1]*w.y
                         + s_l[tt][m4*4+2]*w.z + s_l[tt][m4*4+3]*w.w;
            }
        }
        for (int tt = 0; tt < 8; ++tt)
            WsT[((g*8+tt) * 64 + b) * 128 + tid] = acc[tt];     // layout (t, b, n)
        // SK[j][t][b] = dot(s_t[b], skeys[j])  (gate key-dot, hoisted from scan)
        for (int idx = tid; idx < 160; idx += 128) {
            const int tt = idx / 20;
            const int jj = idx - tt * 20;
            float d = 0.f;
            for (int m = 0; m < 128; ++m) d += s_l[tt][m] * sk_l[jj * 132 + m];
            SK[(jj * 128 + (g*8 + tt)) * 64 + b] = d;
        }
    } else if (bi < 1044) {
        const int j = bi - 1024;
        k_l[tid] = skeys[j * 128 + tid];
        __syncthreads();
        float acc = Vb[tid];
        const float4* vrow = (const float4*)(Vw + tid * 128);
        for (int m4 = 0; m4 < 32; ++m4) {
            const float4 w = vrow[m4];
            acc += k_l[m4*4]*w.x + k_l[m4*4+1]*w.y + k_l[m4*4+2]*w.z + k_l[m4*4+3]*w.w;
        }
        vkey[j * 128 + tid] = acc;
    } else {
        const int b = bi - 1044;
        float sq = 0.f, s1 = 0.f, s2 = 0.f;
        for (int i = 0; i < 16; ++i) sq += E[ques[b*16+i] * 128 + tid];
        for (int i = 0; i < 8;  ++i) s1 += E[ans[(b*8+i)*2+0] * 128 + tid];
        for (int i = 0; i < 8;  ++i) s2 += E[ans[(b*8+i)*2+1] * 128 + tid];
        qv [b*128+tid] = sq * (1.f/16.f);
        a1v[b*128+tid] = s1 * 0.125f;
        a2v[b*128+tid] = s2 * 0.125f;
    }
}

// ---------------------------------------------------------------- scan (MFMA 32x32)
// One block per slot j. 512 threads = 8 waves; wave = (bt2 = wave&1, nt2 = wave>>1).
// Each wave owns ONE 32x32 C tile: C[b][n], b in bt2*32..+31, n in nt2*32..+31.
//   B operand (weights, hi/lo bf16) lives in 64 VGPRs, loaded once from global.
//   A operand (state) read from packed LDS AP (hi16|lo16 of U[b][m], stride 132).
//   3 MFMAs per kc: AhBh + AhBl + AlBh (rel err ~2^-16); fp32 accum.
// C/D layout [verified m74/m101]: col = lane&31, row = (reg&3)+8*(reg>>2)+4*(lane>>5).
// A layout: row = lane&31, k = (lane>>5)*8 + j.
// Per-step globals (sv/skv/wsv) are software-pipelined: issued in step t-1's
// update phase, drained at B2, register-resident when used. xprev[16] keeps the
// lane-owned state in regs (no post-B1 LDS re-read). 2 barriers/step.
__global__ __launch_bounds__(512, 1) void scan_kernel(
    const float* __restrict__ sT, const float* __restrict__ WsT,
    const float* __restrict__ vkey, const float* __restrict__ Uw,
    const float* __restrict__ Ub, const float* __restrict__ SK,
    float* __restrict__ h_out)
{
    __shared__ unsigned int AP[64 * 132];   // packed state, stride 132
    __shared__ float g_l[64];
    __shared__ float wred[8];

    const int j    = blockIdx.x;
    const int tid  = threadIdx.x;        // 512
    const int wave = tid >> 6;           // 0..7
    const int lane = tid & 63;
    const int l32  = lane & 31;
    const int q    = lane >> 5;          // 0..1
    const int bt2  = wave & 1;           // b half
    const int nt2  = wave >> 1;          // n quarter
    const int n    = nt2 * 32 + l32;     // owned output column
    const int gb   = tid >> 3;           // gate: batch row 0..63
    const int gm   = (tid & 7) * 16;     // gate: m-slice (16 words)

    // ---- one-time: weight fragments -> 64 VGPRs (vectorized load) ----
    bf16x8 b_h[8], b_l[8];
    {
        const int k0 = q * 8;
        #pragma unroll
        for (int kc = 0; kc < 8; ++kc) {
            const float4* src = (const float4*)(Uw + n * 128 + kc * 16 + k0);
            const float4 v0 = src[0], v1 = src[1];
            const float xs[8] = {v0.x,v0.y,v0.z,v0.w, v1.x,v1.y,v1.z,v1.w};
            #pragma unroll
            for (int e = 0; e < 8; ++e) {
                const unsigned short h = f2bh(xs[e]);
                b_h[kc][e] = (short)h;
                b_l[kc][e] = (short)f2bh(xs[e] - bh2f(h));
            }
        }
    }
    for (int i = tid; i < 64 * 132; i += 512) AP[i] = 0u;
    const float ubv = Ub[n] + vkey[j * 128 + n];

    // lane-owned state rows (C layout), kept in registers across steps
    float xprev[16];
    #pragma unroll
    for (int r = 0; r < 16; ++r) xprev[r] = 0.f;

    // ---- pipelined globals for step t ----
    float4 sv0, sv1, sv2, sv3;   // gate s-slice
    float  skv;                  // gate key-dot
    float  wsv[16];              // Ws for owned cells
    {
        const float4* s4 = (const float4*)(sT + (0*64 + gb)*128 + gm);
        sv0 = s4[0]; sv1 = s4[1]; sv2 = s4[2]; sv3 = s4[3];
        skv = SK[(j*128 + 0)*64 + gb];
        #pragma unroll
        for (int r = 0; r < 16; ++r) {
            const int brow = bt2*32 + 4*q + (r & 3) + 8*(r >> 2);
            wsv[r] = WsT[(0*64 + brow)*128 + n];
        }
    }
    __syncthreads();

    float inv_s = 1.f;                   // true mem = inv_s * recon(AP)

    for (int t = 0; t < 128; ++t) {
        // ---- gate: g[b] = sigmoid(inv*dot(s_t[b],U[b]) + SK[j][t][b]) ----
        {
            const uint4* u4 = (const uint4*)(AP + gb * 132 + gm);
            const uint4 uw0 = u4[0], uw1 = u4[1], uw2 = u4[2], uw3 = u4[3];
            float d1 = sv0.x*unpack_w(uw0.x) + sv0.y*unpack_w(uw0.y)
                     + sv0.z*unpack_w(uw0.z) + sv0.w*unpack_w(uw0.w)
                     + sv1.x*unpack_w(uw1.x) + sv1.y*unpack_w(uw1.y)
                     + sv1.z*unpack_w(uw1.z) + sv1.w*unpack_w(uw1.w)
                     + sv2.x*unpack_w(uw2.x) + sv2.y*unpack_w(uw2.y)
                     + sv2.z*unpack_w(uw2.z) + sv2.w*unpack_w(uw2.w)
                     + sv3.x*unpack_w(uw3.x) + sv3.y*unpack_w(uw3.y)
                     + sv3.z*unpack_w(uw3.z) + sv3.w*unpack_w(uw3.w);
            d1 += __shfl_xor(d1, 1, 64);
            d1 += __shfl_xor(d1, 2, 64);
            d1 += __shfl_xor(d1, 4, 64);
            if ((tid & 7) == 0) g_l[gb] = 1.f / (1.f + expf(-(inv_s * d1 + skv)));
        }

        // ---- MFMA: acc = U(32b x 128m) . W(32n x 128m)^T tile ----
        f32x16 acc = {0.f,0.f,0.f,0.f,0.f,0.f,0.f,0.f,
                      0.f,0.f,0.f,0.f,0.f,0.f,0.f,0.f};
        {
            const int arow = (bt2*32 + l32) * 132;
            const int k0   = q * 8;
            #pragma unroll
            for (int kc = 0; kc < 8; ++kc) {
                const uint4 p0 = *(const uint4*)(AP + arow + kc*16 + k0);
                const uint4 p1 = *(const uint4*)(AP + arow + kc*16 + k0 + 4);
                bf16x8 ah, al;
                unsigned int* ahd = (unsigned int*)&ah;
                unsigned int* ald = (unsigned int*)&al;
                ahd[0] = __builtin_amdgcn_perm(p0.y, p0.x, 0x07060302u);
                ald[0] = __builtin_amdgcn_perm(p0.y, p0.x, 0x05040100u);
                ahd[1] = __builtin_amdgcn_perm(p0.w, p0.z, 0x07060302u);
                ald[1] = __builtin_amdgcn_perm(p0.w, p0.z, 0x05040100u);
                ahd[2] = __builtin_amdgcn_perm(p1.y, p1.x, 0x07060302u);
                ald[2] = __builtin_amdgcn_perm(p1.y, p1.x, 0x05040100u);
                ahd[3] = __builtin_amdgcn_perm(p1.w, p1.z, 0x07060302u);
                ald[3] = __builtin_amdgcn_perm(p1.w, p1.z, 0x05040100u);
                acc = __builtin_amdgcn_mfma_f32_32x32x16_bf16(ah, b_h[kc], acc, 0, 0, 0);
                acc = __builtin_amdgcn_mfma_f32_32x32x16_bf16(ah, b_l[kc], acc, 0, 0, 0);
                acc = __builtin_amdgcn_mfma_f32_32x32x16_bf16(al, b_h[kc], acc, 0, 0, 0);
            }
        }
        __syncthreads();   // B1: all reads of old AP complete; g_l visible
                           // (no outstanding global loads here -> vmcnt drain free)

        // ---- update owned (b, n) cells in C layout ----
        const float4 gA = *(const float4*)(g_l + bt2*32 + 4*q + 0);
        const float4 gB = *(const float4*)(g_l + bt2*32 + 4*q + 8);
        const float4 gC = *(const float4*)(g_l + bt2*32 + 4*q + 16);
        const float4 gD = *(const float4*)(g_l + bt2*32 + 4*q + 24);
        const float gr[16] = {gA.x,gA.y,gA.z,gA.w, gB.x,gB.y,gB.z,gB.w,
                              gC.x,gC.y,gC.z,gC.w, gD.x,gD.y,gD.z,gD.w};
        float ssq = 0.f;
        #pragma unroll
        for (int r = 0; r < 16; ++r) {
            const int brow = bt2*32 + 4*q + (r & 3) + 8*(r >> 2);
            float hr = fmaf(inv_s, acc[r], ubv + wsv[r]);
            hr = fmaxf(hr, 0.f);                          // h_cand
            const float x = fmaf(inv_s, xprev[r], gr[r] * hr);
            xprev[r] = x;
            AP[brow*132 + n] = pack_w(x);
            ssq = fmaf(x, x, ssq);
        }

        // ---- pipelined prefetch for step t+1 (drains at B2) ----
        {
            const int tn = (t < 127) ? t + 1 : 0;
            const float4* s4 = (const float4*)(sT + (tn*64 + gb)*128 + gm);
            sv0 = s4[0]; sv1 = s4[1]; sv2 = s4[2]; sv3 = s4[3];
            skv = SK[(j*128 + tn)*64 + gb];
            #pragma unroll
            for (int r = 0; r < 16; ++r) {
                const int brow = bt2*32 + 4*q + (r & 3) + 8*(r >> 2);
                wsv[r] = WsT[(tn*64 + brow)*128 + n];
            }
        }

        #pragma unroll
        for (int m = 1; m < 64; m <<= 1) ssq += __shfl_xor(ssq, m, 64);
        if (lane == 0) wred[wave] = ssq;
        __syncthreads();   // B2: AP writes + wave partials visible; prefetch drained
        const float4 w0 = *(const float4*)(wred);
        const float4 w1 = *(const float4*)(wred + 4);
        inv_s = 1.f / sqrtf(w0.x+w0.y+w0.z+w0.w + w1.x+w1.y+w1.z+w1.w);
        // wred re-written only after next step's B1 -> safe
    }

    // ---- h = inv * state, layout (b, j, m) ----
    #pragma unroll
    for (int r = 0; r < 16; ++r) {
        const int brow = bt2*32 + 4*q + (r & 3) + 8*(r >> 2);
        h_out[(brow*20 + j)*128 + n] = inv_s * xprev[r];
    }
}

// ---------------------------------------------------------------- final
__global__ __launch_bounds__(128) void final_kernel(
    const float* __restrict__ h, const float* __restrict__ qv,
    const float* __restrict__ a1v, const float* __restrict__ a2v,
    const float* __restrict__ Hw, const float* __restrict__ Hb,
    float* __restrict__ out)
{
    const int b   = blockIdx.x;
    const int tid = threadIdx.x;    // 128
    __shared__ float hb[20][128];
    __shared__ float ql[128];
    __shared__ float ul[128];
    __shared__ float pl[20];
    __shared__ float lgt[20];
    __shared__ float red1[2], red2[2];

    for (int jj = 0; jj < 20; ++jj) hb[jj][tid] = h[(b*20+jj)*128 + tid];
    ql[tid] = qv[b*128 + tid];
    __syncthreads();
    if (tid < 20) {
        float d = 0.f;
        for (int m = 0; m < 128; ++m) d += hb[tid][m] * ql[m];
        lgt[tid] = d;
    }
    __syncthreads();
    if (tid == 0) {
        float mx = lgt[0];
        for (int jj = 1; jj < 20; ++jj) mx = fmaxf(mx, lgt[jj]);
        float s = 0.f;
        for (int jj = 0; jj < 20; ++jj) { const float e = expf(lgt[jj]-mx); pl[jj] = e; s += e; }
        const float is = 1.f / s;
        for (int jj = 0; jj < 20; ++jj) pl[jj] *= is;
    }
    __syncthreads();
    float u = 0.f;
    for (int jj = 0; jj < 20; ++jj) u += pl[jj] * hb[jj][tid];
    ul[tid] = u;
    __syncthreads();
    float acc = ql[tid] + Hb[tid];
    const float4* hwr = (const float4*)(Hw + tid*128);
    for (int m4 = 0; m4 < 32; ++m4) {
        const float4 w = hwr[m4];
        acc += ul[m4*4]*w.x + ul[m4*4+1]*w.y + ul[m4*4+2]*w.z + ul[m4*4+3]*w.w;
    }
    const float r  = fmaxf(acc, 0.f);
    float y1 = r * a1v[b*128+tid];
    float y2 = r * a2v[b*128+tid];
    #pragma unroll
    for (int mask = 1; mask < 64; mask <<= 1) {
        y1 += __shfl_xor(y1, mask, 64);
        y2 += __shfl_xor(y2, mask, 64);
    }
    if ((tid & 63) == 0) { red1[tid>>6] = y1; red2[tid>>6] = y2; }
    __syncthreads();
    if (tid == 0) {
        const float z1 = red1[0] + red1[1];
        const float z2 = red2[0] + red2[1];
        const float mx = fmaxf(z1, z2);
        const float e1 = expf(z1-mx), e2 = expf(z2-mx);
        const float s  = e1 + e2;
        out[b*2+0] = e1 / s;
        out[b*2+1] = e2 / s;
    }
}

// ---------------------------------------------------------------- launch
extern "C" void kernel_launch(void* const* d_in, const int* in_sizes, int n_in,
                              void* d_out, int out_size, void* d_ws, size_t ws_size,
                              hipStream_t stream)
{
    const int*   ids  = (const int*)  d_in[0];
    const int*   ques = (const int*)  d_in[1];
    const int*   ans  = (const int*)  d_in[2];
    const float* E    = (const float*)d_in[3];
    const float* Uw   = (const float*)d_in[4];
    const float* Ubv  = (const float*)d_in[5];
    const float* Vw   = (const float*)d_in[6];
    const float* Vb   = (const float*)d_in[7];
    const float* Ww   = (const float*)d_in[8];
    const float* Wb   = (const float*)d_in[9];
    const float* sk   = (const float*)d_in[10];
    const float* Hw   = (const float*)d_in[11];
    const float* Hb   = (const float*)d_in[12];

    // workspace (floats): sT 1M | WsT 1M | vkey 2560 | qv/a1v/a2v 3*8192 | h 163840 | SK 163840
    float* ws   = (float*)d_ws;
    float* sT   = ws;
    float* WsT  = sT  + 1048576;
    float* vkey = WsT + 1048576;
    float* qv   = vkey + 2560;
    float* a1v  = qv  + 8192;
    float* a2v  = a1v + 8192;
    float* h    = a2v + 8192;
    float* SK   = h   + 163840;

    prep_kernel<<<1108, 128, 0, stream>>>(ids, ques, ans, E, Ww, Wb, Vw, Vb, sk,
                                          sT, WsT, vkey, qv, a1v, a2v, SK);
    scan_kernel<<<20, 512, 0, stream>>>(sT, WsT, vkey, Uw, Ubv, SK, h);
    final_kernel<<<64, 128, 0, stream>>>(h, qv, a1v, a2v, Hw, Hb, (float*)d_out);
}